// Round 17
// baseline (4077.095 us; speedup 1.0000x reference)
//
#include <hip/hip_runtime.h>

#define EPS 1e-5f
#define PITCH 528   // bytes per LDS row (264 bf16); 132 words % 32 banks = 4
#define T_PER_BLK 4

typedef __attribute__((ext_vector_type(8))) short s16x8;
typedef __attribute__((ext_vector_type(4))) short s16x4;
typedef __attribute__((ext_vector_type(2))) short s16x2;
typedef __attribute__((ext_vector_type(4))) float f32x4;
typedef __attribute__((ext_vector_type(16))) float f32x16;

static __device__ __forceinline__ short f2bf(float x) {
    union { float f; unsigned u; } v; v.f = x;
    return (short)((v.u + 0x7fffu + ((v.u >> 16) & 1u)) >> 16);  // RNE
}
static __device__ __forceinline__ float bf2f(short h) {
    union { float f; unsigned u; } v; v.u = ((unsigned)(unsigned short)h) << 16;
    return v.f;
}
struct bfhl { short hi, lo; };
// exact split: x = hi + lo + r, |r| <= 2^-17 |x|; bf16 lo never denormal
static __device__ __forceinline__ bfhl splitbf(float x) {
    bfhl r; r.hi = f2bf(x); r.lo = f2bf(x - bf2f(r.hi)); return r;
}

// ---- prep: w1 -> 32x32x16 frags (8ft x 16ks); w2 -> 16x16x32 frags (8ft x 8ks) ----
__global__ __launch_bounds__(256) void prep_weights(
    const float* __restrict__ w1, const float* __restrict__ w2,
    short* __restrict__ wb1h, short* __restrict__ wb1l,
    short* __restrict__ wb2h, short* __restrict__ wb2l)
{
    const int t = blockIdx.x * 256 + threadIdx.x;
    const int lane = t & 63, frag = t >> 6;
    short hi[8], lo[8];
    if (frag < 128) {                 // w1: lane l, elem j <- W1[ks*16+(l>>5)*8+j][ft*32+(l&31)]
        const int row0 = (frag & 15) * 16 + (lane >> 5) * 8;
        const int col = (frag >> 4) * 32 + (lane & 31);
        #pragma unroll
        for (int j = 0; j < 8; ++j) {
            const bfhl r = splitbf(w1[(row0 + j) * 256 + col]);
            hi[j] = r.hi; lo[j] = r.lo;
        }
        *reinterpret_cast<s16x8*>(&wb1h[frag * 512 + lane * 8]) = *reinterpret_cast<s16x8*>(hi);
        *reinterpret_cast<s16x8*>(&wb1l[frag * 512 + lane * 8]) = *reinterpret_cast<s16x8*>(lo);
    } else if (frag < 192) {          // w2: lane l, elem j <- W2[ks*32+(l>>4)*8+j][ft2*16+(l&15)]
        const int f = frag - 128;
        const int row0 = ((f & 7) * 32) + ((lane >> 4) * 8);
        const int col = (f >> 3) * 16 + (lane & 15);
        #pragma unroll
        for (int j = 0; j < 8; ++j) {
            const bfhl r = splitbf(w2[(row0 + j) * 128 + col]);
            hi[j] = r.hi; lo[j] = r.lo;
        }
        *reinterpret_cast<s16x8*>(&wb2h[f * 512 + lane * 8]) = *reinterpret_cast<s16x8*>(hi);
        *reinterpret_cast<s16x8*>(&wb2l[f * 512 + lane * 8]) = *reinterpret_cast<s16x8*>(lo);
    }
}

// ---- fused MLP: pipelined, 64 edges/tile, T_PER_BLK tiles/block, 1024 thr ----
// acc = Wh·Hl + Wl·Hh + Wh·Hh (dropped Wl·Hl <= 2^-17 rel)
// HARD CONSTRAINT (R2-R16): LDS > 80KB -> exactly ONE resident block/CU
// (2 blocks/CU corrupts ~0.04 regardless of numerics; overlay at 1/CU is fine).
// 5 barriers/tile; next tile's gather overlaps GEMM2; P1-compute overlaps out.
__global__ __launch_bounds__(1024, 4) void edge_mlp(
    const float* __restrict__ x, const int* __restrict__ ei,
    const float* __restrict__ ln0_g, const float* __restrict__ ln0_b,
    const short* __restrict__ wb1h, const short* __restrict__ wb1l,
    const float* __restrict__ b1,
    const float* __restrict__ ln1_g, const float* __restrict__ ln1_b,
    const short* __restrict__ wb2h, const short* __restrict__ wb2l,
    const float* __restrict__ b2,
    const float* __restrict__ ln2_g, const float* __restrict__ ln2_b,
    const float* __restrict__ wp, const float* __restrict__ bp,
    const float* __restrict__ ww, const float* __restrict__ bw,
    float* __restrict__ out, int E, int ntiles)
{
    __shared__ __align__(16) short Ah[64 * 264];   // h0 hi/lo (33KB each)
    __shared__ __align__(16) short Al[64 * 264];
    __shared__ __align__(16) short Bh[64 * 264];   // h1 hi/lo
    __shared__ __align__(16) short Bl[64 * 264];
    __shared__ __align__(8) float red[16][64][2];  // stats partials
    __shared__ __align__(8) float red2[16][64][2]; // heads partials  (total ~148KB)

    const int tid = threadIdx.x, lane = tid & 63, w = tid >> 6;   // w in 0..15
    const int g = lane >> 4, c15 = lane & 15;
    const int l31 = lane & 31, lh = lane >> 5;
    const int ft = w >> 1, et = w & 1;       // GEMM1 mapping (32x32)
    const int ft2 = w >> 1, hf = w & 1;      // GEMM2 mapping (16x16)
    const int tbase = blockIdx.x * T_PER_BLK;
    const int L = (ntiles - tbase < T_PER_BLK) ? (ntiles - tbase) : T_PER_BLK;

    // hoisted coefficients
    const int c = 2 * lane;
    const float ga = ln0_g[c], gb = ln0_g[c + 1], gc = ln0_g[128 + c], gd = ln0_g[129 + c];
    const float ba = ln0_b[c], bb = ln0_b[c + 1], bc = ln0_b[128 + c], bd = ln0_b[129 + c];
    float bi2[4], gv2[4], bv2[4], pv2[4], wv2[4];
    *reinterpret_cast<float4*>(bi2) = *reinterpret_cast<const float4*>(&b2[ft2 * 16 + g * 4]);
    *reinterpret_cast<float4*>(gv2) = *reinterpret_cast<const float4*>(&ln2_g[ft2 * 16 + g * 4]);
    *reinterpret_cast<float4*>(bv2) = *reinterpret_cast<const float4*>(&ln2_b[ft2 * 16 + g * 4]);
    *reinterpret_cast<float4*>(pv2) = *reinterpret_cast<const float4*>(&wp[ft2 * 16 + g * 4]);
    *reinterpret_cast<float4*>(wv2) = *reinterpret_cast<const float4*>(&ww[ft2 * 16 + g * 4]);

    float2 pf[8];   // prefetched x rows: 4 edges x {src,dst}

    // ---- P1 load (tile t) -> pf ----
    auto p1_load = [&](long t) {
        #pragma unroll
        for (int e8 = 0; e8 < 4; ++e8) {
            const long idx = t * 64 + w * 4 + e8;
            #pragma unroll
            for (int s = 0; s < 2; ++s) {
                const int si = (idx < E) ? ei[(long)s * E + idx] : 0;
                pf[e8 * 2 + s] = *reinterpret_cast<const float2*>(&x[(long)si * 128 + c]);
            }
        }
    };
    // ---- P1 compute: feats + LN0 + split -> A ----
    auto p1_compute = [&]() {
        char* hhc = (char*)Ah;
        char* hlc = (char*)Al;
        #pragma unroll
        for (int e8 = 0; e8 < 4; ++e8) {
            const int e = w * 4 + e8;
            const float2 sv = pf[e8 * 2 + 0], dv = pf[e8 * 2 + 1];
            const float a0 = sv.x + dv.x, a1 = sv.y + dv.y;
            const float m0 = sv.x * dv.x, m1 = sv.y * dv.y;
            float s = a0 + a1 + m0 + m1;
            float q = a0 * a0 + a1 * a1 + m0 * m0 + m1 * m1;
            #pragma unroll
            for (int o = 32; o; o >>= 1) { s += __shfl_xor(s, o); q += __shfl_xor(q, o); }
            const float mu = s * (1.f / 256.f);
            const float rs = rsqrtf(q * (1.f / 256.f) - mu * mu + EPS);
            const bfhl r0 = splitbf((a0 - mu) * rs * ga + ba);
            const bfhl r1 = splitbf((a1 - mu) * rs * gb + bb);
            const bfhl r2 = splitbf((m0 - mu) * rs * gc + bc);
            const bfhl r3 = splitbf((m1 - mu) * rs * gd + bd);
            s16x2 p0h, p0l, p1h, p1l;
            p0h[0] = r0.hi; p0l[0] = r0.lo;
            p0h[1] = r1.hi; p0l[1] = r1.lo;
            p1h[0] = r2.hi; p1l[0] = r2.lo;
            p1h[1] = r3.hi; p1l[1] = r3.lo;
            const int o0 = e * PITCH + 4 * lane;
            const int o1 = e * PITCH + 256 + 4 * lane;
            *reinterpret_cast<s16x2*>(hhc + o0) = p0h;
            *reinterpret_cast<s16x2*>(hhc + o1) = p1h;
            *reinterpret_cast<s16x2*>(hlc + o0) = p0l;
            *reinterpret_cast<s16x2*>(hlc + o1) = p1l;
        }
    };

    // ---- prologue: produce A(t0) ----
    p1_load(tbase);
    p1_compute();
    __syncthreads();

    for (int i = 0; i < L; ++i) {
        const long ti = tbase + i;
        const long base = ti * 64;

        // ===== B0: GEMM1 32x32x16 (reads A) + LN1 stats partial =====
        f32x16 acc1 = {};
        {
            const char* hhc = (const char*)Ah;
            const char* hlc = (const char*)Al;
            const int boff = (et * 32 + l31) * PITCH + lh * 16;
            for (int ks = 0; ks < 16; ++ks) {
                const int fo = (ft * 16 + ks) * 512 + lane * 8;
                const s16x8 ah = *reinterpret_cast<const s16x8*>(&wb1h[fo]);
                const s16x8 al = *reinterpret_cast<const s16x8*>(&wb1l[fo]);
                const int off = boff + ks * 32;
                const s16x8 bh = *reinterpret_cast<const s16x8*>(hhc + off);
                const s16x8 bl = *reinterpret_cast<const s16x8*>(hlc + off);
                acc1 = __builtin_amdgcn_mfma_f32_32x32x16_bf16(ah, bl, acc1, 0, 0, 0);
                acc1 = __builtin_amdgcn_mfma_f32_32x32x16_bf16(al, bh, acc1, 0, 0, 0);
                acc1 = __builtin_amdgcn_mfma_f32_32x32x16_bf16(ah, bh, acc1, 0, 0, 0);
            }
            float bi[4][4];
            #pragma unroll
            for (int g2 = 0; g2 < 4; ++g2)
                *reinterpret_cast<float4*>(bi[g2]) =
                    *reinterpret_cast<const float4*>(&b1[ft * 32 + g2 * 8 + 4 * lh]);
            float s = 0.f, q = 0.f;
            #pragma unroll
            for (int r = 0; r < 16; ++r) {
                const float v2 = acc1[r] + bi[r >> 2][r & 3];
                acc1[r] = v2; s += v2; q += v2 * v2;
            }
            s += __shfl_xor(s, 32); q += __shfl_xor(q, 32);
            if (lane < 32) { red[w][et * 32 + lane][0] = s; red[w][et * 32 + lane][1] = q; }
        }
        __syncthreads();

        // ===== B1: per-lane LN1 stat finalize + apply -> B =====
        {
            const int e1 = et * 32 + l31;
            float S = 0.f, Q = 0.f;
            #pragma unroll
            for (int f = 0; f < 8; ++f) { S += red[2 * f + et][e1][0]; Q += red[2 * f + et][e1][1]; }
            const float mu = S * (1.f / 256.f);
            const float rs = rsqrtf(Q * (1.f / 256.f) - mu * mu + EPS);
            char* hhc = (char*)Bh;
            char* hlc = (char*)Bl;
            #pragma unroll
            for (int g2 = 0; g2 < 4; ++g2) {
                const int f0 = ft * 32 + g2 * 8 + 4 * lh;
                float gv[4], bv[4];
                *reinterpret_cast<float4*>(gv) = *reinterpret_cast<const float4*>(&ln1_g[f0]);
                *reinterpret_cast<float4*>(bv) = *reinterpret_cast<const float4*>(&ln1_b[f0]);
                s16x4 ph, pl;
                #pragma unroll
                for (int ii = 0; ii < 4; ++ii) {
                    const bfhl rr = splitbf(fmaxf((acc1[g2 * 4 + ii] - mu) * rs * gv[ii] + bv[ii], 0.f));
                    ph[ii] = rr.hi; pl[ii] = rr.lo;
                }
                const int off = e1 * PITCH + f0 * 2;
                *reinterpret_cast<s16x4*>(hhc + off) = ph;
                *reinterpret_cast<s16x4*>(hlc + off) = pl;
            }
        }
        __syncthreads();

        // ===== B2: prefetch next tile's gather; GEMM2 16x16x32 (reads B); LN2 stats partial =====
        if (i + 1 < L) p1_load(ti + 1);   // loads issue first; MFMAs below hide latency
        f32x4 acc2[2] = {};
        {
            const char* hhc = (const char*)Bh;
            const char* hlc = (const char*)Bl;
            for (int ks = 0; ks < 8; ++ks) {
                const int fo = (ft2 * 8 + ks) * 512 + lane * 8;
                const s16x8 ah = *reinterpret_cast<const s16x8*>(&wb2h[fo]);
                const s16x8 al = *reinterpret_cast<const s16x8*>(&wb2l[fo]);
                const int kb = ks * 64 + g * 16;
                #pragma unroll
                for (int ntl = 0; ntl < 2; ++ntl) {
                    const int e = (2 * hf + ntl) * 16 + c15;
                    const int off = e * PITCH + kb;
                    const s16x8 bh = *reinterpret_cast<const s16x8*>(hhc + off);
                    const s16x8 bl = *reinterpret_cast<const s16x8*>(hlc + off);
                    acc2[ntl] = __builtin_amdgcn_mfma_f32_16x16x32_bf16(ah, bl, acc2[ntl], 0, 0, 0);
                    acc2[ntl] = __builtin_amdgcn_mfma_f32_16x16x32_bf16(al, bh, acc2[ntl], 0, 0, 0);
                    acc2[ntl] = __builtin_amdgcn_mfma_f32_16x16x32_bf16(ah, bh, acc2[ntl], 0, 0, 0);
                }
            }
            float s[2], q[2];
            #pragma unroll
            for (int ntl = 0; ntl < 2; ++ntl) {
                s[ntl] = 0.f; q[ntl] = 0.f;
                #pragma unroll
                for (int r = 0; r < 4; ++r) {
                    const float v2 = acc2[ntl][r] + bi2[r];
                    acc2[ntl][r] = v2; s[ntl] += v2; q[ntl] += v2 * v2;
                }
            }
            #pragma unroll
            for (int ntl = 0; ntl < 2; ++ntl) {
                s[ntl] += __shfl_xor(s[ntl], 16); q[ntl] += __shfl_xor(q[ntl], 16);
                s[ntl] += __shfl_xor(s[ntl], 32); q[ntl] += __shfl_xor(q[ntl], 32);
            }
            if ((g >> 1) == hf) {
                red[w][lane][0] = (g & 1) ? s[1] : s[0];
                red[w][lane][1] = (g & 1) ? q[1] : q[0];
            }
        }
        __syncthreads();

        // ===== B3: per-lane LN2 stat finalize + apply + heads partial -> red2 =====
        {
            float pp[2], ws2[2];
            #pragma unroll
            for (int ntl = 0; ntl < 2; ++ntl) {
                const int e = (2 * hf + ntl) * 16 + c15;
                float S = 0.f, Q = 0.f;
                #pragma unroll
                for (int k = 0; k < 8; ++k) { S += red[2 * k + hf][e][0]; Q += red[2 * k + hf][e][1]; }
                const float mu = S * (1.f / 128.f);
                const float rs = rsqrtf(Q * (1.f / 128.f) - mu * mu + EPS);
                pp[ntl] = 0.f; ws2[ntl] = 0.f;
                #pragma unroll
                for (int r = 0; r < 4; ++r) {
                    const float t = fmaxf((acc2[ntl][r] - mu) * rs * gv2[r] + bv2[r], 0.f);
                    pp[ntl] += t * pv2[r]; ws2[ntl] += t * wv2[r];
                }
            }
            #pragma unroll
            for (int ntl = 0; ntl < 2; ++ntl) {
                pp[ntl] += __shfl_xor(pp[ntl], 16); ws2[ntl] += __shfl_xor(ws2[ntl], 16);
                pp[ntl] += __shfl_xor(pp[ntl], 32); ws2[ntl] += __shfl_xor(ws2[ntl], 32);
            }
            if ((g >> 1) == hf) {
                red2[w][lane][0] = (g & 1) ? pp[1] : pp[0];
                red2[w][lane][1] = (g & 1) ? ws2[1] : ws2[0];
            }
        }
        __syncthreads();

        // ===== B4: output (tid<64) + P1-compute(t+1) -> A =====
        if (tid < 64 && base + tid < E) {
            const int hE = tid >> 5;
            float P = bp[0], W = bw[0];
            #pragma unroll
            for (int w2 = 0; w2 < 16; w2 += 2) { P += red2[w2 + hE][tid][0]; W += red2[w2 + hE][tid][1]; }
            out[base + tid] = P;
            out[(long)E + base + tid] = fmaxf(W, 0.f);
        }
        if (i + 1 < L) p1_compute();
        __syncthreads();
    }
}

extern "C" void kernel_launch(void* const* d_in, const int* in_sizes, int n_in,
                              void* d_out, int out_size, void* d_ws, size_t ws_size,
                              hipStream_t stream) {
    const float* x     = (const float*)d_in[0];
    const int*   ei    = (const int*)  d_in[1];
    const float* ln0_g = (const float*)d_in[2];
    const float* ln0_b = (const float*)d_in[3];
    const float* w1    = (const float*)d_in[4];
    const float* b1    = (const float*)d_in[5];
    const float* ln1_g = (const float*)d_in[6];
    const float* ln1_b = (const float*)d_in[7];
    const float* w2    = (const float*)d_in[8];
    const float* b2    = (const float*)d_in[9];
    const float* ln2_g = (const float*)d_in[10];
    const float* ln2_b = (const float*)d_in[11];
    const float* wp    = (const float*)d_in[12];
    const float* bp    = (const float*)d_in[13];
    const float* ww    = (const float*)d_in[14];
    const float* bw    = (const float*)d_in[15];

    short* wb1h = (short*)d_ws;             // 128 frags * 512
    short* wb1l = wb1h + 128 * 512;
    short* wb2h = wb1l + 128 * 512;         // 64 frags * 512
    short* wb2l = wb2h + 64 * 512;          // total 384KB

    const int E = in_sizes[1] / 2;
    const int ntiles = (E + 63) / 64;
    const int nblk = (ntiles + T_PER_BLK - 1) / T_PER_BLK;
    prep_weights<<<48, 256, 0, stream>>>(w1, w2, wb1h, wb1l, wb2h, wb2l);
    edge_mlp<<<nblk, 1024, 0, stream>>>(x, ei, ln0_g, ln0_b, wb1h, wb1l, b1,
                                        ln1_g, ln1_b, wb2h, wb2l, b2, ln2_g, ln2_b,
                                        wp, bp, ww, bw, (float*)d_out, E, ntiles);
}

// Round 18
// 3715.069 us; speedup vs baseline: 1.0974x; 1.0974x over previous
//
#include <hip/hip_runtime.h>

#define EPS 1e-5f
#define PITCH 528   // bytes per LDS row (264 bf16); 132 words % 32 banks = 4
#define T_PER_BLK 4

typedef __attribute__((ext_vector_type(8))) short s16x8;
typedef __attribute__((ext_vector_type(4))) short s16x4;
typedef __attribute__((ext_vector_type(2))) short s16x2;
typedef __attribute__((ext_vector_type(16))) float f32x16;

static __device__ __forceinline__ short f2bf(float x) {
    union { float f; unsigned u; } v; v.f = x;
    return (short)((v.u + 0x7fffu + ((v.u >> 16) & 1u)) >> 16);  // RNE
}
static __device__ __forceinline__ float bf2f(short h) {
    union { float f; unsigned u; } v; v.u = ((unsigned)(unsigned short)h) << 16;
    return v.f;
}
struct bfhl { short hi, lo; };
// exact split: x = hi + lo + r, |r| <= 2^-17 |x|; bf16 lo never denormal
static __device__ __forceinline__ bfhl splitbf(float x) {
    bfhl r; r.hi = f2bf(x); r.lo = f2bf(x - bf2f(r.hi)); return r;
}

// ---- prep: repack weights into split-bf16 32x32x16 MFMA A-fragments of W^T ----
// w1 (256x256): frag(ft 0..7, ks 0..15): lane l, elem j <- W1[ks*16+(l>>5)*8+j][ft*32+(l&31)]
// w2 (256x128): frag(ft2 0..3, ks 0..15): lane l, elem j <- W2[ks*16+(l>>5)*8+j][ft2*32+(l&31)]
__global__ __launch_bounds__(256) void prep_weights(
    const float* __restrict__ w1, const float* __restrict__ w2,
    short* __restrict__ wb1h, short* __restrict__ wb1l,
    short* __restrict__ wb2h, short* __restrict__ wb2l)
{
    const int t = blockIdx.x * 256 + threadIdx.x;
    const int lane = t & 63, frag = t >> 6;
    short hi[8], lo[8];
    if (frag < 128) {                 // w1: 8 ft x 16 ks
        const int row0 = (frag & 15) * 16 + (lane >> 5) * 8;
        const int col = (frag >> 4) * 32 + (lane & 31);
        #pragma unroll
        for (int j = 0; j < 8; ++j) {
            const bfhl r = splitbf(w1[(row0 + j) * 256 + col]);
            hi[j] = r.hi; lo[j] = r.lo;
        }
        *reinterpret_cast<s16x8*>(&wb1h[frag * 512 + lane * 8]) = *reinterpret_cast<s16x8*>(hi);
        *reinterpret_cast<s16x8*>(&wb1l[frag * 512 + lane * 8]) = *reinterpret_cast<s16x8*>(lo);
    } else if (frag < 192) {          // w2: 4 ft2 x 16 ks
        const int f = frag - 128;
        const int row0 = (f & 15) * 16 + (lane >> 5) * 8;
        const int col = (f >> 4) * 32 + (lane & 31);
        #pragma unroll
        for (int j = 0; j < 8; ++j) {
            const bfhl r = splitbf(w2[(row0 + j) * 128 + col]);
            hi[j] = r.hi; lo[j] = r.lo;
        }
        *reinterpret_cast<s16x8*>(&wb2h[f * 512 + lane * 8]) = *reinterpret_cast<s16x8*>(hi);
        *reinterpret_cast<s16x8*>(&wb2l[f * 512 + lane * 8]) = *reinterpret_cast<s16x8*>(lo);
    }
}

// ---- fused MLP: 128 edges/tile, T_PER_BLK tiles/block, 1024 thr, all-32x32 GEMMs ----
// acc = Wh·Hl + Wl·Hh + Wh·Hh (dropped Wl·Hl <= 2^-17 rel)
// HARD CONSTRAINT (R2-R16): LDS > 80KB -> exactly ONE resident block/CU
// (2 blocks/CU corrupts ~0.04 regardless of numerics; h-overlay at 1/CU is fine).
// 5 barriers/tile: per-lane stat finalize (no idle tid<128 phases), wave-local
// sidx (no LDS/barrier), output phase merged with next tile's P1.
// NO register prefetch state (R17's pf[] spilled to scratch at 1024 thr).
__global__ __launch_bounds__(1024, 4) void edge_mlp(
    const float* __restrict__ x, const int* __restrict__ ei,
    const float* __restrict__ ln0_g, const float* __restrict__ ln0_b,
    const short* __restrict__ wb1h, const short* __restrict__ wb1l,
    const float* __restrict__ b1,
    const float* __restrict__ ln1_g, const float* __restrict__ ln1_b,
    const short* __restrict__ wb2h, const short* __restrict__ wb2l,
    const float* __restrict__ b2,
    const float* __restrict__ ln2_g, const float* __restrict__ ln2_b,
    const float* __restrict__ wp, const float* __restrict__ bp,
    const float* __restrict__ ww, const float* __restrict__ bw,
    float* __restrict__ out, int E, int ntiles)
{
    __shared__ __align__(16) short hh[128 * 264];   // 67.6KB: h0 then h1 (overlay)
    __shared__ __align__(16) short hl[128 * 264];   // 67.6KB
    __shared__ __align__(8) float red[16][64][2];   // 8KB: stats partials (wave-local idx)
    __shared__ __align__(8) float red2[16][32][2];  // 4KB: heads partials  (~147KB total)

    const int tid = threadIdx.x, lane = tid & 63, w = tid >> 6;   // w in 0..15
    const int l31 = lane & 31, lh = lane >> 5;
    const int ft = w >> 1, ep = w & 1;       // GEMM1: feats ft*32..+32, edges ep*64..+64
    const int ft2 = w >> 2, et2 = w & 3;     // GEMM2: feats ft2*32..+32, edges et2*32..+32
    const int tbase = blockIdx.x * T_PER_BLK;
    const int L = (ntiles - tbase < T_PER_BLK) ? (ntiles - tbase) : T_PER_BLK;

    // hoisted per-thread coefficients
    const int c = 2 * lane;
    const float ga = ln0_g[c], gb = ln0_g[c + 1], gc = ln0_g[128 + c], gd = ln0_g[129 + c];
    const float ba = ln0_b[c], bb = ln0_b[c + 1], bc = ln0_b[128 + c], bd = ln0_b[129 + c];

    // ---- P1: wave-local sidx + gather + LN0 + split -> h (h0) ----
    // wave w owns edges w*8 .. w*8+7 of the tile
    auto run_p1 = [&](long tt) {
        int si = 0;
        if (lane < 16) {
            const long idx = tt * 128 + w * 8 + (lane >> 1);
            const int s = lane & 1;
            si = (idx < E) ? ei[(long)s * E + idx] : 0;
        }
        char* hhc = (char*)hh;
        char* hlc = (char*)hl;
        #pragma unroll
        for (int e8 = 0; e8 < 8; ++e8) {
            const int s0 = __shfl(si, e8 * 2 + 0);
            const int s1 = __shfl(si, e8 * 2 + 1);
            const int e = w * 8 + e8;
            const float2 sv = *reinterpret_cast<const float2*>(&x[(long)s0 * 128 + c]);
            const float2 dv = *reinterpret_cast<const float2*>(&x[(long)s1 * 128 + c]);
            const float a0 = sv.x + dv.x, a1 = sv.y + dv.y;
            const float m0 = sv.x * dv.x, m1 = sv.y * dv.y;
            float s = a0 + a1 + m0 + m1;
            float q = a0 * a0 + a1 * a1 + m0 * m0 + m1 * m1;
            #pragma unroll
            for (int o = 32; o; o >>= 1) { s += __shfl_xor(s, o); q += __shfl_xor(q, o); }
            const float mu = s * (1.f / 256.f);
            const float rs = rsqrtf(q * (1.f / 256.f) - mu * mu + EPS);
            const bfhl r0 = splitbf((a0 - mu) * rs * ga + ba);
            const bfhl r1 = splitbf((a1 - mu) * rs * gb + bb);
            const bfhl r2 = splitbf((m0 - mu) * rs * gc + bc);
            const bfhl r3 = splitbf((m1 - mu) * rs * gd + bd);
            s16x2 p0h, p0l, p1h, p1l;
            p0h[0] = r0.hi; p0l[0] = r0.lo;
            p0h[1] = r1.hi; p0l[1] = r1.lo;
            p1h[0] = r2.hi; p1l[0] = r2.lo;
            p1h[1] = r3.hi; p1l[1] = r3.lo;
            const int o0 = e * PITCH + 4 * lane;
            const int o1 = e * PITCH + 256 + 4 * lane;
            *reinterpret_cast<s16x2*>(hhc + o0) = p0h;
            *reinterpret_cast<s16x2*>(hhc + o1) = p1h;
            *reinterpret_cast<s16x2*>(hlc + o0) = p0l;
            *reinterpret_cast<s16x2*>(hlc + o1) = p1l;
        }
    };

    run_p1(tbase);
    __syncthreads();

    for (int i = 0; i < L; ++i) {
        const long base = (long)(tbase + i) * 128;

        // ===== B0: GEMM1 32x32x16 (reads h0) + bias + LN1 stats partial =====
        f32x16 acc1[2] = {};
        {
            const char* hhc = (const char*)hh;
            const char* hlc = (const char*)hl;
            const int boffA = (ep * 64 + l31) * PITCH + lh * 16;
            const int boffB = (ep * 64 + 32 + l31) * PITCH + lh * 16;
            for (int ks = 0; ks < 16; ++ks) {
                const int fo = (ft * 16 + ks) * 512 + lane * 8;
                const s16x8 ah = *reinterpret_cast<const s16x8*>(&wb1h[fo]);
                const s16x8 al = *reinterpret_cast<const s16x8*>(&wb1l[fo]);
                const int offA = boffA + ks * 32;
                const s16x8 bhA = *reinterpret_cast<const s16x8*>(hhc + offA);
                const s16x8 blA = *reinterpret_cast<const s16x8*>(hlc + offA);
                acc1[0] = __builtin_amdgcn_mfma_f32_32x32x16_bf16(ah, blA, acc1[0], 0, 0, 0);
                acc1[0] = __builtin_amdgcn_mfma_f32_32x32x16_bf16(al, bhA, acc1[0], 0, 0, 0);
                acc1[0] = __builtin_amdgcn_mfma_f32_32x32x16_bf16(ah, bhA, acc1[0], 0, 0, 0);
                const int offB = boffB + ks * 32;
                const s16x8 bhB = *reinterpret_cast<const s16x8*>(hhc + offB);
                const s16x8 blB = *reinterpret_cast<const s16x8*>(hlc + offB);
                acc1[1] = __builtin_amdgcn_mfma_f32_32x32x16_bf16(ah, blB, acc1[1], 0, 0, 0);
                acc1[1] = __builtin_amdgcn_mfma_f32_32x32x16_bf16(al, bhB, acc1[1], 0, 0, 0);
                acc1[1] = __builtin_amdgcn_mfma_f32_32x32x16_bf16(ah, bhB, acc1[1], 0, 0, 0);
            }
            float bi[4][4];
            #pragma unroll
            for (int g2 = 0; g2 < 4; ++g2)
                *reinterpret_cast<float4*>(bi[g2]) =
                    *reinterpret_cast<const float4*>(&b1[ft * 32 + g2 * 8 + 4 * lh]);
            #pragma unroll
            for (int t = 0; t < 2; ++t) {
                float s = 0.f, q = 0.f;
                #pragma unroll
                for (int r = 0; r < 16; ++r) {
                    const float v2 = acc1[t][r] + bi[r >> 2][r & 3];
                    acc1[t][r] = v2; s += v2; q += v2 * v2;
                }
                s += __shfl_xor(s, 32); q += __shfl_xor(q, 32);
                if (lane < 32) { red[w][t * 32 + lane][0] = s; red[w][t * 32 + lane][1] = q; }
            }
        }
        __syncthreads();

        // ===== B1: per-lane LN1 finalize + apply + relu -> h1 (overlays h0) =====
        {
            char* hhc = (char*)hh;
            char* hlc = (char*)hl;
            #pragma unroll
            for (int t = 0; t < 2; ++t) {
                const int el = t * 32 + l31;              // wave-local edge idx
                const int e1 = ep * 64 + el;              // tile edge idx
                float S = 0.f, Q = 0.f;
                #pragma unroll
                for (int f = 0; f < 8; ++f) { S += red[2 * f + ep][el][0]; Q += red[2 * f + ep][el][1]; }
                const float mu = S * (1.f / 256.f);
                const float rs = rsqrtf(Q * (1.f / 256.f) - mu * mu + EPS);
                #pragma unroll
                for (int g2 = 0; g2 < 4; ++g2) {
                    const int f0 = ft * 32 + g2 * 8 + 4 * lh;
                    float gv[4], bv[4];
                    *reinterpret_cast<float4*>(gv) = *reinterpret_cast<const float4*>(&ln1_g[f0]);
                    *reinterpret_cast<float4*>(bv) = *reinterpret_cast<const float4*>(&ln1_b[f0]);
                    s16x4 ph, pl;
                    #pragma unroll
                    for (int ii = 0; ii < 4; ++ii) {
                        const bfhl rr = splitbf(fmaxf((acc1[t][g2 * 4 + ii] - mu) * rs * gv[ii] + bv[ii], 0.f));
                        ph[ii] = rr.hi; pl[ii] = rr.lo;
                    }
                    const int off = e1 * PITCH + f0 * 2;
                    *reinterpret_cast<s16x4*>(hhc + off) = ph;
                    *reinterpret_cast<s16x4*>(hlc + off) = pl;
                }
            }
        }
        __syncthreads();

        // ===== B2: GEMM2 32x32x16 (reads h1) + bias + LN2 stats partial =====
        f32x16 acc2 = {};
        {
            const char* hhc = (const char*)hh;
            const char* hlc = (const char*)hl;
            const int e2 = et2 * 32 + l31;
            const int boff2 = e2 * PITCH + lh * 16;
            for (int ks = 0; ks < 16; ++ks) {
                const int fo = (ft2 * 16 + ks) * 512 + lane * 8;
                const s16x8 ah = *reinterpret_cast<const s16x8*>(&wb2h[fo]);
                const s16x8 al = *reinterpret_cast<const s16x8*>(&wb2l[fo]);
                const int off = boff2 + ks * 32;
                const s16x8 bh = *reinterpret_cast<const s16x8*>(hhc + off);
                const s16x8 bl = *reinterpret_cast<const s16x8*>(hlc + off);
                acc2 = __builtin_amdgcn_mfma_f32_32x32x16_bf16(ah, bl, acc2, 0, 0, 0);
                acc2 = __builtin_amdgcn_mfma_f32_32x32x16_bf16(al, bh, acc2, 0, 0, 0);
                acc2 = __builtin_amdgcn_mfma_f32_32x32x16_bf16(ah, bh, acc2, 0, 0, 0);
            }
            float bi[4][4];
            #pragma unroll
            for (int g2 = 0; g2 < 4; ++g2)
                *reinterpret_cast<float4*>(bi[g2]) =
                    *reinterpret_cast<const float4*>(&b2[ft2 * 32 + g2 * 8 + 4 * lh]);
            float s = 0.f, q = 0.f;
            #pragma unroll
            for (int r = 0; r < 16; ++r) {
                const float v2 = acc2[r] + bi[r >> 2][r & 3];
                acc2[r] = v2; s += v2; q += v2 * v2;
            }
            s += __shfl_xor(s, 32); q += __shfl_xor(q, 32);
            if (lane < 32) { red[w][lane][0] = s; red[w][lane][1] = q; }
        }
        __syncthreads();

        // ===== B3: per-lane LN2 finalize + apply + heads partial -> red2 =====
        {
            float S = 0.f, Q = 0.f;
            #pragma unroll
            for (int f2 = 0; f2 < 4; ++f2) { S += red[4 * f2 + et2][l31][0]; Q += red[4 * f2 + et2][l31][1]; }
            const float mu = S * (1.f / 128.f);
            const float rs = rsqrtf(Q * (1.f / 128.f) - mu * mu + EPS);
            float pp = 0.f, ws2 = 0.f;
            #pragma unroll
            for (int g2 = 0; g2 < 4; ++g2) {
                const int f0 = ft2 * 32 + g2 * 8 + 4 * lh;
                float gv[4], bv[4], pv[4], wv[4];
                *reinterpret_cast<float4*>(gv) = *reinterpret_cast<const float4*>(&ln2_g[f0]);
                *reinterpret_cast<float4*>(bv) = *reinterpret_cast<const float4*>(&ln2_b[f0]);
                *reinterpret_cast<float4*>(pv) = *reinterpret_cast<const float4*>(&wp[f0]);
                *reinterpret_cast<float4*>(wv) = *reinterpret_cast<const float4*>(&ww[f0]);
                #pragma unroll
                for (int ii = 0; ii < 4; ++ii) {
                    const float t = fmaxf((acc2[g2 * 4 + ii] - mu) * rs * gv[ii] + bv[ii], 0.f);
                    pp += t * pv[ii]; ws2 += t * wv[ii];
                }
            }
            pp += __shfl_xor(pp, 32); ws2 += __shfl_xor(ws2, 32);
            if (lane < 32) { red2[w][lane][0] = pp; red2[w][lane][1] = ws2; }
        }
        __syncthreads();

        // ===== B4: output (tid<128) + P1(t+1) -> h0 (merged phase) =====
        if (tid < 128 && base + tid < E) {
            const int q5 = tid >> 5, l = tid & 31;
            float P = bp[0], W = bw[0];
            #pragma unroll
            for (int f2 = 0; f2 < 4; ++f2) { P += red2[4 * f2 + q5][l][0]; W += red2[4 * f2 + q5][l][1]; }
            out[base + tid] = P;                         // logits
            out[(long)E + base + tid] = fmaxf(W, 0.f);   // relu'd weights
        }
        if (i + 1 < L) run_p1(tbase + i + 1);
        __syncthreads();
    }
}

extern "C" void kernel_launch(void* const* d_in, const int* in_sizes, int n_in,
                              void* d_out, int out_size, void* d_ws, size_t ws_size,
                              hipStream_t stream) {
    const float* x     = (const float*)d_in[0];
    const int*   ei    = (const int*)  d_in[1];
    const float* ln0_g = (const float*)d_in[2];
    const float* ln0_b = (const float*)d_in[3];
    const float* w1    = (const float*)d_in[4];
    const float* b1    = (const float*)d_in[5];
    const float* ln1_g = (const float*)d_in[6];
    const float* ln1_b = (const float*)d_in[7];
    const float* w2    = (const float*)d_in[8];
    const float* b2    = (const float*)d_in[9];
    const float* ln2_g = (const float*)d_in[10];
    const float* ln2_b = (const float*)d_in[11];
    const float* wp    = (const float*)d_in[12];
    const float* bp    = (const float*)d_in[13];
    const float* ww    = (const float*)d_in[14];
    const float* bw    = (const float*)d_in[15];

    short* wb1h = (short*)d_ws;             // 128 frags * 512
    short* wb1l = wb1h + 128 * 512;
    short* wb2h = wb1l + 128 * 512;         // 64 frags * 512
    short* wb2l = wb2h + 64 * 512;          // total 384KB

    const int E = in_sizes[1] / 2;
    const int ntiles = (E + 127) / 128;
    const int nblk = (ntiles + T_PER_BLK - 1) / T_PER_BLK;
    prep_weights<<<48, 256, 0, stream>>>(w1, w2, wb1h, wb1l, wb2h, wb2l);
    edge_mlp<<<nblk, 1024, 0, stream>>>(x, ei, ln0_g, ln0_b, wb1h, wb1l, b1,
                                        ln1_g, ln1_b, wb2h, wb2l, b2, ln2_g, ln2_b,
                                        wp, bp, ww, bw, (float*)d_out, E, ntiles);
}

// Round 19
// 842.102 us; speedup vs baseline: 4.8416x; 4.4117x over previous
//
#include <hip/hip_runtime.h>

#define EPS 1e-5f
#define PITCH 528   // bytes per LDS row (264 bf16); 132 words % 32 banks = 4

typedef __attribute__((ext_vector_type(8))) short s16x8;
typedef __attribute__((ext_vector_type(4))) short s16x4;
typedef __attribute__((ext_vector_type(2))) short s16x2;
typedef __attribute__((ext_vector_type(16))) float f32x16;

static __device__ __forceinline__ short f2bf(float x) {
    union { float f; unsigned u; } v; v.f = x;
    return (short)((v.u + 0x7fffu + ((v.u >> 16) & 1u)) >> 16);  // RNE
}
static __device__ __forceinline__ float bf2f(short h) {
    union { float f; unsigned u; } v; v.u = ((unsigned)(unsigned short)h) << 16;
    return v.f;
}
struct bfhl { short hi, lo; };
// exact split: x = hi + lo + r, |r| <= 2^-17 |x|; bf16 lo never denormal
static __device__ __forceinline__ bfhl splitbf(float x) {
    bfhl r; r.hi = f2bf(x); r.lo = f2bf(x - bf2f(r.hi)); return r;
}

// ---- prep: repack weights into split-bf16 32x32x16 MFMA A-fragments of W^T ----
// w1 (256x256): frag(ft 0..7, ks 0..15): lane l, elem j <- W1[ks*16+(l>>5)*8+j][ft*32+(l&31)]
// w2 (256x128): frag(ft2 0..3, ks 0..15): lane l, elem j <- W2[ks*16+(l>>5)*8+j][ft2*32+(l&31)]
__global__ __launch_bounds__(256) void prep_weights(
    const float* __restrict__ w1, const float* __restrict__ w2,
    short* __restrict__ wb1h, short* __restrict__ wb1l,
    short* __restrict__ wb2h, short* __restrict__ wb2l)
{
    const int t = blockIdx.x * 256 + threadIdx.x;
    const int lane = t & 63, frag = t >> 6;
    short hi[8], lo[8];
    if (frag < 128) {                 // w1: 8 ft x 16 ks
        const int row0 = (frag & 15) * 16 + (lane >> 5) * 8;
        const int col = (frag >> 4) * 32 + (lane & 31);
        #pragma unroll
        for (int j = 0; j < 8; ++j) {
            const bfhl r = splitbf(w1[(row0 + j) * 256 + col]);
            hi[j] = r.hi; lo[j] = r.lo;
        }
        *reinterpret_cast<s16x8*>(&wb1h[frag * 512 + lane * 8]) = *reinterpret_cast<s16x8*>(hi);
        *reinterpret_cast<s16x8*>(&wb1l[frag * 512 + lane * 8]) = *reinterpret_cast<s16x8*>(lo);
    } else if (frag < 192) {          // w2: 4 ft2 x 16 ks
        const int f = frag - 128;
        const int row0 = (f & 15) * 16 + (lane >> 5) * 8;
        const int col = (f >> 4) * 32 + (lane & 31);
        #pragma unroll
        for (int j = 0; j < 8; ++j) {
            const bfhl r = splitbf(w2[(row0 + j) * 128 + col]);
            hi[j] = r.hi; lo[j] = r.lo;
        }
        *reinterpret_cast<s16x8*>(&wb2h[f * 512 + lane * 8]) = *reinterpret_cast<s16x8*>(hi);
        *reinterpret_cast<s16x8*>(&wb2l[f * 512 + lane * 8]) = *reinterpret_cast<s16x8*>(lo);
    }
}

// ---- fused MLP: 128 edges/block, 1024 thr (16 waves), all-32x32 split-bf16 GEMMs ----
// acc = Wh·Hl + Wl·Hh + Wh·Hh (dropped Wl·Hl <= 2^-17 rel)
// HARD CONSTRAINT (R2-R16): LDS > 80KB -> exactly ONE resident block/CU
// (2 blocks/CU corrupts ~0.04 regardless of numerics; h-overlay at 1/CU is fine).
// STRAIGHT-LINE single-tile body (R17/R18 lesson: tile-loops/lambdas at 1024
// threads spill to scratch). 5 barriers: wave-local sidx (no LDS phase),
// per-lane stat finalize (no idle tid<128 phases, no stat[] array).
__global__ __launch_bounds__(1024, 4) void edge_mlp(
    const float* __restrict__ x, const int* __restrict__ ei,
    const float* __restrict__ ln0_g, const float* __restrict__ ln0_b,
    const short* __restrict__ wb1h, const short* __restrict__ wb1l,
    const float* __restrict__ b1,
    const float* __restrict__ ln1_g, const float* __restrict__ ln1_b,
    const short* __restrict__ wb2h, const short* __restrict__ wb2l,
    const float* __restrict__ b2,
    const float* __restrict__ ln2_g, const float* __restrict__ ln2_b,
    const float* __restrict__ wp, const float* __restrict__ bp,
    const float* __restrict__ ww, const float* __restrict__ bw,
    float* __restrict__ out, int E)
{
    __shared__ __align__(16) short hh[128 * 264];   // 67.6KB: h0 then h1 (overlay)
    __shared__ __align__(16) short hl[128 * 264];   // 67.6KB
    __shared__ __align__(8) float red[16][64][2];   // 8KB: stats partials (wave-local)
    __shared__ __align__(8) float red2[16][32][2];  // 4KB: heads partials  (~147KB)

    const int tid = threadIdx.x, lane = tid & 63, w = tid >> 6;   // w in 0..15
    const int l31 = lane & 31, lh = lane >> 5;
    const int ft = w >> 1, ep = w & 1;       // GEMM1: feats ft*32..+32, edges ep*64..+64
    const int ft2 = w >> 2, et2 = w & 3;     // GEMM2: feats ft2*32..+32, edges et2*32..+32
    const long base = (long)blockIdx.x * 128;

    // ---------- P1: wave-local sidx + gather + LN0 + split -> h0 ----------
    // wave w owns edges w*8 .. w*8+7
    {
        int si = 0;
        if (lane < 16) {
            const long idx = base + w * 8 + (lane >> 1);
            const int s = lane & 1;
            si = (idx < E) ? ei[(long)s * E + idx] : 0;
        }
        const int c = 2 * lane;
        const float ga = ln0_g[c], gb = ln0_g[c + 1], gc = ln0_g[128 + c], gd = ln0_g[129 + c];
        const float ba = ln0_b[c], bb = ln0_b[c + 1], bc = ln0_b[128 + c], bd = ln0_b[129 + c];
        char* hhc = (char*)hh;
        char* hlc = (char*)hl;
        #pragma unroll
        for (int e8 = 0; e8 < 8; ++e8) {
            const int s0 = __shfl(si, e8 * 2 + 0);
            const int s1 = __shfl(si, e8 * 2 + 1);
            const int e = w * 8 + e8;
            const float2 sv = *reinterpret_cast<const float2*>(&x[(long)s0 * 128 + c]);
            const float2 dv = *reinterpret_cast<const float2*>(&x[(long)s1 * 128 + c]);
            const float a0 = sv.x + dv.x, a1 = sv.y + dv.y;
            const float m0 = sv.x * dv.x, m1 = sv.y * dv.y;
            float s = a0 + a1 + m0 + m1;
            float q = a0 * a0 + a1 * a1 + m0 * m0 + m1 * m1;
            #pragma unroll
            for (int o = 32; o; o >>= 1) { s += __shfl_xor(s, o); q += __shfl_xor(q, o); }
            const float mu = s * (1.f / 256.f);
            const float rs = rsqrtf(q * (1.f / 256.f) - mu * mu + EPS);
            const bfhl r0 = splitbf((a0 - mu) * rs * ga + ba);
            const bfhl r1 = splitbf((a1 - mu) * rs * gb + bb);
            const bfhl r2 = splitbf((m0 - mu) * rs * gc + bc);
            const bfhl r3 = splitbf((m1 - mu) * rs * gd + bd);
            s16x2 p0h, p0l, p1h, p1l;
            p0h[0] = r0.hi; p0l[0] = r0.lo;
            p0h[1] = r1.hi; p0l[1] = r1.lo;
            p1h[0] = r2.hi; p1l[0] = r2.lo;
            p1h[1] = r3.hi; p1l[1] = r3.lo;
            const int o0 = e * PITCH + 4 * lane;
            const int o1 = e * PITCH + 256 + 4 * lane;
            *reinterpret_cast<s16x2*>(hhc + o0) = p0h;
            *reinterpret_cast<s16x2*>(hhc + o1) = p1h;
            *reinterpret_cast<s16x2*>(hlc + o0) = p0l;
            *reinterpret_cast<s16x2*>(hlc + o1) = p1l;
        }
    }
    __syncthreads();   // [1]

    // ---------- B0: GEMM1 32x32x16 (reads h0) + bias + LN1 stats partial ----------
    f32x16 acc1[2] = {};
    {
        const char* hhc = (const char*)hh;
        const char* hlc = (const char*)hl;
        const int boffA = (ep * 64 + l31) * PITCH + lh * 16;
        const int boffB = (ep * 64 + 32 + l31) * PITCH + lh * 16;
        for (int ks = 0; ks < 16; ++ks) {
            const int fo = (ft * 16 + ks) * 512 + lane * 8;
            const s16x8 ah = *reinterpret_cast<const s16x8*>(&wb1h[fo]);
            const s16x8 al = *reinterpret_cast<const s16x8*>(&wb1l[fo]);
            const int offA = boffA + ks * 32;
            const s16x8 bhA = *reinterpret_cast<const s16x8*>(hhc + offA);
            const s16x8 blA = *reinterpret_cast<const s16x8*>(hlc + offA);
            acc1[0] = __builtin_amdgcn_mfma_f32_32x32x16_bf16(ah, blA, acc1[0], 0, 0, 0);
            acc1[0] = __builtin_amdgcn_mfma_f32_32x32x16_bf16(al, bhA, acc1[0], 0, 0, 0);
            acc1[0] = __builtin_amdgcn_mfma_f32_32x32x16_bf16(ah, bhA, acc1[0], 0, 0, 0);
            const int offB = boffB + ks * 32;
            const s16x8 bhB = *reinterpret_cast<const s16x8*>(hhc + offB);
            const s16x8 blB = *reinterpret_cast<const s16x8*>(hlc + offB);
            acc1[1] = __builtin_amdgcn_mfma_f32_32x32x16_bf16(ah, blB, acc1[1], 0, 0, 0);
            acc1[1] = __builtin_amdgcn_mfma_f32_32x32x16_bf16(al, bhB, acc1[1], 0, 0, 0);
            acc1[1] = __builtin_amdgcn_mfma_f32_32x32x16_bf16(ah, bhB, acc1[1], 0, 0, 0);
        }
        float bi[4][4];
        #pragma unroll
        for (int g2 = 0; g2 < 4; ++g2)
            *reinterpret_cast<float4*>(bi[g2]) =
                *reinterpret_cast<const float4*>(&b1[ft * 32 + g2 * 8 + 4 * lh]);
        #pragma unroll
        for (int t = 0; t < 2; ++t) {
            float s = 0.f, q = 0.f;
            #pragma unroll
            for (int r = 0; r < 16; ++r) {
                const float v2 = acc1[t][r] + bi[r >> 2][r & 3];
                acc1[t][r] = v2; s += v2; q += v2 * v2;
            }
            s += __shfl_xor(s, 32); q += __shfl_xor(q, 32);
            if (lane < 32) { red[w][t * 32 + lane][0] = s; red[w][t * 32 + lane][1] = q; }
        }
    }
    __syncthreads();   // [2]

    // ---------- B1: per-lane LN1 finalize + apply + relu -> h1 (overlays h0) ----------
    {
        char* hhc = (char*)hh;
        char* hlc = (char*)hl;
        #pragma unroll
        for (int t = 0; t < 2; ++t) {
            const int el = t * 32 + l31;              // wave-local edge idx
            const int e1 = ep * 64 + el;              // tile edge idx
            float S = 0.f, Q = 0.f;
            #pragma unroll
            for (int f = 0; f < 8; ++f) { S += red[2 * f + ep][el][0]; Q += red[2 * f + ep][el][1]; }
            const float mu = S * (1.f / 256.f);
            const float rs = rsqrtf(Q * (1.f / 256.f) - mu * mu + EPS);
            #pragma unroll
            for (int g2 = 0; g2 < 4; ++g2) {
                const int f0 = ft * 32 + g2 * 8 + 4 * lh;
                float gv[4], bv[4];
                *reinterpret_cast<float4*>(gv) = *reinterpret_cast<const float4*>(&ln1_g[f0]);
                *reinterpret_cast<float4*>(bv) = *reinterpret_cast<const float4*>(&ln1_b[f0]);
                s16x4 ph, pl;
                #pragma unroll
                for (int ii = 0; ii < 4; ++ii) {
                    const bfhl rr = splitbf(fmaxf((acc1[t][g2 * 4 + ii] - mu) * rs * gv[ii] + bv[ii], 0.f));
                    ph[ii] = rr.hi; pl[ii] = rr.lo;
                }
                const int off = e1 * PITCH + f0 * 2;
                *reinterpret_cast<s16x4*>(hhc + off) = ph;
                *reinterpret_cast<s16x4*>(hlc + off) = pl;
            }
        }
    }
    __syncthreads();   // [3]

    // ---------- B2: GEMM2 32x32x16 (reads h1) + bias + LN2 stats partial ----------
    f32x16 acc2 = {};
    {
        const char* hhc = (const char*)hh;
        const char* hlc = (const char*)hl;
        const int e2 = et2 * 32 + l31;
        const int boff2 = e2 * PITCH + lh * 16;
        for (int ks = 0; ks < 16; ++ks) {
            const int fo = (ft2 * 16 + ks) * 512 + lane * 8;
            const s16x8 ah = *reinterpret_cast<const s16x8*>(&wb2h[fo]);
            const s16x8 al = *reinterpret_cast<const s16x8*>(&wb2l[fo]);
            const int off = boff2 + ks * 32;
            const s16x8 bh = *reinterpret_cast<const s16x8*>(hhc + off);
            const s16x8 bl = *reinterpret_cast<const s16x8*>(hlc + off);
            acc2 = __builtin_amdgcn_mfma_f32_32x32x16_bf16(ah, bl, acc2, 0, 0, 0);
            acc2 = __builtin_amdgcn_mfma_f32_32x32x16_bf16(al, bh, acc2, 0, 0, 0);
            acc2 = __builtin_amdgcn_mfma_f32_32x32x16_bf16(ah, bh, acc2, 0, 0, 0);
        }
        float bi[4][4];
        #pragma unroll
        for (int g2 = 0; g2 < 4; ++g2)
            *reinterpret_cast<float4*>(bi[g2]) =
                *reinterpret_cast<const float4*>(&b2[ft2 * 32 + g2 * 8 + 4 * lh]);
        float s = 0.f, q = 0.f;
        #pragma unroll
        for (int r = 0; r < 16; ++r) {
            const float v2 = acc2[r] + bi[r >> 2][r & 3];
            acc2[r] = v2; s += v2; q += v2 * v2;
        }
        s += __shfl_xor(s, 32); q += __shfl_xor(q, 32);
        if (lane < 32) { red[w][lane][0] = s; red[w][lane][1] = q; }
    }
    __syncthreads();   // [4]

    // ---------- B3: per-lane LN2 finalize + apply + heads partial -> red2 ----------
    {
        float S = 0.f, Q = 0.f;
        #pragma unroll
        for (int f2 = 0; f2 < 4; ++f2) { S += red[4 * f2 + et2][l31][0]; Q += red[4 * f2 + et2][l31][1]; }
        const float mu = S * (1.f / 128.f);
        const float rs = rsqrtf(Q * (1.f / 128.f) - mu * mu + EPS);
        float pp = 0.f, ws2 = 0.f;
        #pragma unroll
        for (int g2 = 0; g2 < 4; ++g2) {
            const int f0 = ft2 * 32 + g2 * 8 + 4 * lh;
            float gv[4], bv[4], pv[4], wv[4];
            *reinterpret_cast<float4*>(gv) = *reinterpret_cast<const float4*>(&ln2_g[f0]);
            *reinterpret_cast<float4*>(bv) = *reinterpret_cast<const float4*>(&ln2_b[f0]);
            *reinterpret_cast<float4*>(pv) = *reinterpret_cast<const float4*>(&wp[f0]);
            *reinterpret_cast<float4*>(wv) = *reinterpret_cast<const float4*>(&ww[f0]);
            #pragma unroll
            for (int ii = 0; ii < 4; ++ii) {
                const float t = fmaxf((acc2[g2 * 4 + ii] - mu) * rs * gv[ii] + bv[ii], 0.f);
                pp += t * pv[ii]; ws2 += t * wv[ii];
            }
        }
        pp += __shfl_xor(pp, 32); ws2 += __shfl_xor(ws2, 32);
        if (lane < 32) { red2[w][lane][0] = pp; red2[w][lane][1] = ws2; }
    }
    __syncthreads();   // [5]

    // ---------- B4: output ----------
    if (tid < 128 && base + tid < E) {
        const int q5 = tid >> 5, l = tid & 31;
        float P = bp[0], W = bw[0];
        #pragma unroll
        for (int f2 = 0; f2 < 4; ++f2) { P += red2[4 * f2 + q5][l][0]; W += red2[4 * f2 + q5][l][1]; }
        out[base + tid] = P;                         // logits
        out[(long)E + base + tid] = fmaxf(W, 0.f);   // relu'd weights
    }
}

extern "C" void kernel_launch(void* const* d_in, const int* in_sizes, int n_in,
                              void* d_out, int out_size, void* d_ws, size_t ws_size,
                              hipStream_t stream) {
    const float* x     = (const float*)d_in[0];
    const int*   ei    = (const int*)  d_in[1];
    const float* ln0_g = (const float*)d_in[2];
    const float* ln0_b = (const float*)d_in[3];
    const float* w1    = (const float*)d_in[4];
    const float* b1    = (const float*)d_in[5];
    const float* ln1_g = (const float*)d_in[6];
    const float* ln1_b = (const float*)d_in[7];
    const float* w2    = (const float*)d_in[8];
    const float* b2    = (const float*)d_in[9];
    const float* ln2_g = (const float*)d_in[10];
    const float* ln2_b = (const float*)d_in[11];
    const float* wp    = (const float*)d_in[12];
    const float* bp    = (const float*)d_in[13];
    const float* ww    = (const float*)d_in[14];
    const float* bw    = (const float*)d_in[15];

    short* wb1h = (short*)d_ws;             // 128 frags * 512
    short* wb1l = wb1h + 128 * 512;
    short* wb2h = wb1l + 128 * 512;         // 64 frags * 512
    short* wb2l = wb2h + 64 * 512;          // total 384KB

    const int E = in_sizes[1] / 2;
    prep_weights<<<48, 256, 0, stream>>>(w1, w2, wb1h, wb1l, wb2h, wb2l);
    edge_mlp<<<(E + 127) / 128, 1024, 0, stream>>>(x, ei, ln0_g, ln0_b, wb1h, wb1l, b1,
                                                   ln1_g, ln1_b, wb2h, wb2l, b2, ln2_g, ln2_b,
                                                   wp, bp, ww, bw, (float*)d_out, E);
}

// Round 20
// 581.829 us; speedup vs baseline: 7.0074x; 1.4473x over previous
//
#include <hip/hip_runtime.h>

#define EPS 1e-5f
#define PITCH 528   // bytes per LDS row (264 f16); 132 words % 32 banks = 4

typedef __attribute__((ext_vector_type(8))) _Float16 f16x8;
typedef __attribute__((ext_vector_type(4))) _Float16 f16x4v;
typedef __attribute__((ext_vector_type(2))) _Float16 f16x2v;
typedef __attribute__((ext_vector_type(16))) float f32x16;

// ---- prep: repack weights into fp16 32x32x16 MFMA A-fragments of W^T ----
// w1 (256x256): frag(ft 0..7, ks 0..15): lane l, elem j <- W1[ks*16+(l>>5)*8+j][ft*32+(l&31)]
// w2 (256x128): frag(ft2 0..3, ks 0..15): lane l, elem j <- W2[ks*16+(l>>5)*8+j][ft2*32+(l&31)]
__global__ __launch_bounds__(256) void prep_weights(
    const float* __restrict__ w1, const float* __restrict__ w2,
    _Float16* __restrict__ wb1, _Float16* __restrict__ wb2)
{
    const int t = blockIdx.x * 256 + threadIdx.x;
    const int lane = t & 63, frag = t >> 6;
    _Float16 v[8];
    if (frag < 128) {                 // w1: 8 ft x 16 ks
        const int row0 = (frag & 15) * 16 + (lane >> 5) * 8;
        const int col = (frag >> 4) * 32 + (lane & 31);
        #pragma unroll
        for (int j = 0; j < 8; ++j) v[j] = (_Float16)w1[(row0 + j) * 256 + col];
        *reinterpret_cast<f16x8*>(&wb1[frag * 512 + lane * 8]) = *reinterpret_cast<f16x8*>(v);
    } else if (frag < 192) {          // w2: 4 ft2 x 16 ks
        const int f = frag - 128;
        const int row0 = (f & 15) * 16 + (lane >> 5) * 8;
        const int col = (f >> 4) * 32 + (lane & 31);
        #pragma unroll
        for (int j = 0; j < 8; ++j) v[j] = (_Float16)w2[(row0 + j) * 128 + col];
        *reinterpret_cast<f16x8*>(&wb2[f * 512 + lane * 8]) = *reinterpret_cast<f16x8*>(v);
    }
}

// ---- fused MLP: 128 edges/block, 1024 thr (16 waves), plain-fp16 1-MFMA GEMMs ----
// DECISIVE NUMERICS TEST: R2-R12's fp16 failures were all confounded by the
// 2-blocks/CU corruption law (only R7/R9 ran at 1 block/CU, both split-bf16).
// This build: plain fp16, single activation plane, at 1 block/CU.
// HARD CONSTRAINT (R2-R16): LDS > 80KB -> ONE resident block/CU. Natural LDS
// would be 79.9KB (= 2 blocks fit!) so hh carries a +16KB pad -> 96KB.
// STRAIGHT-LINE single-tile body (R17/R18: loops/lambdas at 1024 thr spill).
__global__ __launch_bounds__(1024, 4) void edge_mlp(
    const float* __restrict__ x, const int* __restrict__ ei,
    const float* __restrict__ ln0_g, const float* __restrict__ ln0_b,
    const _Float16* __restrict__ wb1, const float* __restrict__ b1,
    const float* __restrict__ ln1_g, const float* __restrict__ ln1_b,
    const _Float16* __restrict__ wb2, const float* __restrict__ b2,
    const float* __restrict__ ln2_g, const float* __restrict__ ln2_b,
    const float* __restrict__ wp, const float* __restrict__ bp,
    const float* __restrict__ ww, const float* __restrict__ bw,
    float* __restrict__ out, int E)
{
    // 128*264 = h rows (67.6KB) + 8192 pad elements (16KB) = 83.9KB total.
    // Pad keeps LDS > 80KB -> 1 block/CU (the corruption interlock).
    __shared__ __align__(16) _Float16 hh[128 * 264 + 8192];
    __shared__ __align__(8) float red[16][64][2];   // 8KB
    __shared__ __align__(8) float red2[16][32][2];  // 4KB  (total ~96KB)

    const int tid = threadIdx.x, lane = tid & 63, w = tid >> 6;   // w in 0..15
    const int l31 = lane & 31, lh = lane >> 5;
    const int ft = w >> 1, ep = w & 1;       // GEMM1: feats ft*32..+32, edges ep*64..+64
    const int ft2 = w >> 2, et2 = w & 3;     // GEMM2: feats ft2*32..+32, edges et2*32..+32
    const long base = (long)blockIdx.x * 128;

    // ---------- P1: wave-local sidx + gather + LN0 -> h0 (fp16, single plane) ----------
    // wave w owns edges w*8 .. w*8+7
    {
        int si = 0;
        if (lane < 16) {
            const long idx = base + w * 8 + (lane >> 1);
            const int s = lane & 1;
            si = (idx < E) ? ei[(long)s * E + idx] : 0;
        }
        const int c = 2 * lane;
        const float ga = ln0_g[c], gb = ln0_g[c + 1], gc = ln0_g[128 + c], gd = ln0_g[129 + c];
        const float ba = ln0_b[c], bb = ln0_b[c + 1], bc = ln0_b[128 + c], bd = ln0_b[129 + c];
        char* hhc = (char*)hh;
        #pragma unroll
        for (int e8 = 0; e8 < 8; ++e8) {
            const int s0 = __shfl(si, e8 * 2 + 0);
            const int s1 = __shfl(si, e8 * 2 + 1);
            const int e = w * 8 + e8;
            const float2 sv = *reinterpret_cast<const float2*>(&x[(long)s0 * 128 + c]);
            const float2 dv = *reinterpret_cast<const float2*>(&x[(long)s1 * 128 + c]);
            const float a0 = sv.x + dv.x, a1 = sv.y + dv.y;
            const float m0 = sv.x * dv.x, m1 = sv.y * dv.y;
            float s = a0 + a1 + m0 + m1;
            float q = a0 * a0 + a1 * a1 + m0 * m0 + m1 * m1;
            #pragma unroll
            for (int o = 32; o; o >>= 1) { s += __shfl_xor(s, o); q += __shfl_xor(q, o); }
            const float mu = s * (1.f / 256.f);
            const float rs = rsqrtf(q * (1.f / 256.f) - mu * mu + EPS);
            f16x2v p0, p1;
            p0[0] = (_Float16)((a0 - mu) * rs * ga + ba);
            p0[1] = (_Float16)((a1 - mu) * rs * gb + bb);
            p1[0] = (_Float16)((m0 - mu) * rs * gc + bc);
            p1[1] = (_Float16)((m1 - mu) * rs * gd + bd);
            const int o0 = e * PITCH + 4 * lane;
            const int o1 = e * PITCH + 256 + 4 * lane;
            *reinterpret_cast<f16x2v*>(hhc + o0) = p0;
            *reinterpret_cast<f16x2v*>(hhc + o1) = p1;
        }
    }
    __syncthreads();   // [1]

    // ---------- B0: GEMM1 32x32x16 fp16 (reads h0) + bias + LN1 stats partial ----------
    f32x16 acc1[2] = {};
    {
        const char* hhc = (const char*)hh;
        const int boffA = (ep * 64 + l31) * PITCH + lh * 16;
        const int boffB = (ep * 64 + 32 + l31) * PITCH + lh * 16;
        for (int ks = 0; ks < 16; ++ks) {
            const f16x8 a = *reinterpret_cast<const f16x8*>(&wb1[(ft * 16 + ks) * 512 + lane * 8]);
            const f16x8 bA = *reinterpret_cast<const f16x8*>(hhc + boffA + ks * 32);
            acc1[0] = __builtin_amdgcn_mfma_f32_32x32x16_f16(a, bA, acc1[0], 0, 0, 0);
            const f16x8 bB = *reinterpret_cast<const f16x8*>(hhc + boffB + ks * 32);
            acc1[1] = __builtin_amdgcn_mfma_f32_32x32x16_f16(a, bB, acc1[1], 0, 0, 0);
        }
        float bi[4][4];
        #pragma unroll
        for (int g2 = 0; g2 < 4; ++g2)
            *reinterpret_cast<float4*>(bi[g2]) =
                *reinterpret_cast<const float4*>(&b1[ft * 32 + g2 * 8 + 4 * lh]);
        #pragma unroll
        for (int t = 0; t < 2; ++t) {
            float s = 0.f, q = 0.f;
            #pragma unroll
            for (int r = 0; r < 16; ++r) {
                const float v2 = acc1[t][r] + bi[r >> 2][r & 3];
                acc1[t][r] = v2; s += v2; q += v2 * v2;
            }
            s += __shfl_xor(s, 32); q += __shfl_xor(q, 32);
            if (lane < 32) { red[w][t * 32 + lane][0] = s; red[w][t * 32 + lane][1] = q; }
        }
    }
    __syncthreads();   // [2]

    // ---------- B1: per-lane LN1 finalize + apply + relu -> h1 (overlays h0) ----------
    {
        char* hhc = (char*)hh;
        #pragma unroll
        for (int t = 0; t < 2; ++t) {
            const int el = t * 32 + l31;
            const int e1 = ep * 64 + el;
            float S = 0.f, Q = 0.f;
            #pragma unroll
            for (int f = 0; f < 8; ++f) { S += red[2 * f + ep][el][0]; Q += red[2 * f + ep][el][1]; }
            const float mu = S * (1.f / 256.f);
            const float rs = rsqrtf(Q * (1.f / 256.f) - mu * mu + EPS);
            #pragma unroll
            for (int g2 = 0; g2 < 4; ++g2) {
                const int f0 = ft * 32 + g2 * 8 + 4 * lh;
                float gv[4], bv[4];
                *reinterpret_cast<float4*>(gv) = *reinterpret_cast<const float4*>(&ln1_g[f0]);
                *reinterpret_cast<float4*>(bv) = *reinterpret_cast<const float4*>(&ln1_b[f0]);
                f16x4v pk;
                #pragma unroll
                for (int ii = 0; ii < 4; ++ii)
                    pk[ii] = (_Float16)fmaxf((acc1[t][g2 * 4 + ii] - mu) * rs * gv[ii] + bv[ii], 0.f);
                *reinterpret_cast<f16x4v*>(hhc + e1 * PITCH + f0 * 2) = pk;
            }
        }
    }
    __syncthreads();   // [3]

    // ---------- B2: GEMM2 32x32x16 fp16 (reads h1) + bias + LN2 stats partial ----------
    f32x16 acc2 = {};
    {
        const char* hhc = (const char*)hh;
        const int e2 = et2 * 32 + l31;
        const int boff2 = e2 * PITCH + lh * 16;
        for (int ks = 0; ks < 16; ++ks) {
            const f16x8 a = *reinterpret_cast<const f16x8*>(&wb2[(ft2 * 16 + ks) * 512 + lane * 8]);
            const f16x8 b = *reinterpret_cast<const f16x8*>(hhc + boff2 + ks * 32);
            acc2 = __builtin_amdgcn_mfma_f32_32x32x16_f16(a, b, acc2, 0, 0, 0);
        }
        float bi[4][4];
        #pragma unroll
        for (int g2 = 0; g2 < 4; ++g2)
            *reinterpret_cast<float4*>(bi[g2]) =
                *reinterpret_cast<const float4*>(&b2[ft2 * 32 + g2 * 8 + 4 * lh]);
        float s = 0.f, q = 0.f;
        #pragma unroll
        for (int r = 0; r < 16; ++r) {
            const float v2 = acc2[r] + bi[r >> 2][r & 3];
            acc2[r] = v2; s += v2; q += v2 * v2;
        }
        s += __shfl_xor(s, 32); q += __shfl_xor(q, 32);
        if (lane < 32) { red[w][lane][0] = s; red[w][lane][1] = q; }
    }
    __syncthreads();   // [4]

    // ---------- B3: per-lane LN2 finalize + apply + heads partial -> red2 ----------
    {
        float S = 0.f, Q = 0.f;
        #pragma unroll
        for (int f2 = 0; f2 < 4; ++f2) { S += red[4 * f2 + et2][l31][0]; Q += red[4 * f2 + et2][l31][1]; }
        const float mu = S * (1.f / 128.f);
        const float rs = rsqrtf(Q * (1.f / 128.f) - mu * mu + EPS);
        float pp = 0.f, ws2 = 0.f;
        #pragma unroll
        for (int g2 = 0; g2 < 4; ++g2) {
            const int f0 = ft2 * 32 + g2 * 8 + 4 * lh;
            float gv[4], bv[4], pv[4], wv[4];
            *reinterpret_cast<float4*>(gv) = *reinterpret_cast<const float4*>(&ln2_g[f0]);
            *reinterpret_cast<float4*>(bv) = *reinterpret_cast<const float4*>(&ln2_b[f0]);
            *reinterpret_cast<float4*>(pv) = *reinterpret_cast<const float4*>(&wp[f0]);
            *reinterpret_cast<float4*>(wv) = *reinterpret_cast<const float4*>(&ww[f0]);
            #pragma unroll
            for (int ii = 0; ii < 4; ++ii) {
                const float t = fmaxf((acc2[g2 * 4 + ii] - mu) * rs * gv[ii] + bv[ii], 0.f);
                pp += t * pv[ii]; ws2 += t * wv[ii];
            }
        }
        pp += __shfl_xor(pp, 32); ws2 += __shfl_xor(ws2, 32);
        if (lane < 32) { red2[w][lane][0] = pp; red2[w][lane][1] = ws2; }
    }
    __syncthreads();   // [5]

    // ---------- B4: output ----------
    if (tid < 128 && base + tid < E) {
        const int q5 = tid >> 5, l = tid & 31;
        float P = bp[0], W = bw[0];
        #pragma unroll
        for (int f2 = 0; f2 < 4; ++f2) { P += red2[4 * f2 + q5][l][0]; W += red2[4 * f2 + q5][l][1]; }
        out[base + tid] = P;                         // logits
        out[(long)E + base + tid] = fmaxf(W, 0.f);   // relu'd weights
    }
}

extern "C" void kernel_launch(void* const* d_in, const int* in_sizes, int n_in,
                              void* d_out, int out_size, void* d_ws, size_t ws_size,
                              hipStream_t stream) {
    const float* x     = (const float*)d_in[0];
    const int*   ei    = (const int*)  d_in[1];
    const float* ln0_g = (const float*)d_in[2];
    const float* ln0_b = (const float*)d_in[3];
    const float* w1    = (const float*)d_in[4];
    const float* b1    = (const float*)d_in[5];
    const float* ln1_g = (const float*)d_in[6];
    const float* ln1_b = (const float*)d_in[7];
    const float* w2    = (const float*)d_in[8];
    const float* b2    = (const float*)d_in[9];
    const float* ln2_g = (const float*)d_in[10];
    const float* ln2_b = (const float*)d_in[11];
    const float* wp    = (const float*)d_in[12];
    const float* bp    = (const float*)d_in[13];
    const float* ww    = (const float*)d_in[14];
    const float* bw    = (const float*)d_in[15];

    _Float16* wb1 = (_Float16*)d_ws;        // 128 frags * 512 = 128KB
    _Float16* wb2 = wb1 + 128 * 512;        // 64 frags * 512 = 64KB

    const int E = in_sizes[1] / 2;
    prep_weights<<<48, 256, 0, stream>>>(w1, w2, wb1, wb2);
    edge_mlp<<<(E + 127) / 128, 1024, 0, stream>>>(x, ei, ln0_g, ln0_b, wb1, b1,
                                                   ln1_g, ln1_b, wb2, b2, ln2_g, ln2_b,
                                                   wp, bp, ww, bw, (float*)d_out, E);
}

// Round 21
// 576.345 us; speedup vs baseline: 7.0740x; 1.0095x over previous
//
#include <hip/hip_runtime.h>

#define EPS 1e-5f
#define PITCH 528   // bytes per LDS row (264 f16); 132 words % 32 banks = 4

typedef __attribute__((ext_vector_type(8))) _Float16 f16x8;
typedef __attribute__((ext_vector_type(4))) _Float16 f16x4v;
typedef __attribute__((ext_vector_type(2))) _Float16 f16x2v;
typedef __attribute__((ext_vector_type(16))) float f32x16;

// ---- prep: convert node features x (fp32) -> fp16 (halves gather footprint:
// 51MB -> 25.6MB, deep L3/L2 residency; R20 showed FETCH=478MB ~= whole runtime)
__global__ __launch_bounds__(256) void prep_x(const float* __restrict__ x,
                                              _Float16* __restrict__ x16, long n)
{
    const long i = ((long)blockIdx.x * 256 + threadIdx.x) * 8;
    if (i + 7 < n) {
        const float4 a = *reinterpret_cast<const float4*>(&x[i]);
        const float4 b = *reinterpret_cast<const float4*>(&x[i + 4]);
        f16x8 v;
        v[0] = (_Float16)a.x; v[1] = (_Float16)a.y; v[2] = (_Float16)a.z; v[3] = (_Float16)a.w;
        v[4] = (_Float16)b.x; v[5] = (_Float16)b.y; v[6] = (_Float16)b.z; v[7] = (_Float16)b.w;
        *reinterpret_cast<f16x8*>(&x16[i]) = v;
    }
}

// ---- prep: repack weights into fp16 32x32x16 MFMA A-fragments of W^T ----
// w1 (256x256): frag(ft 0..7, ks 0..15): lane l, elem j <- W1[ks*16+(l>>5)*8+j][ft*32+(l&31)]
// w2 (256x128): frag(ft2 0..3, ks 0..15): lane l, elem j <- W2[ks*16+(l>>5)*8+j][ft2*32+(l&31)]
__global__ __launch_bounds__(256) void prep_weights(
    const float* __restrict__ w1, const float* __restrict__ w2,
    _Float16* __restrict__ wb1, _Float16* __restrict__ wb2)
{
    const int t = blockIdx.x * 256 + threadIdx.x;
    const int lane = t & 63, frag = t >> 6;
    _Float16 v[8];
    if (frag < 128) {                 // w1: 8 ft x 16 ks
        const int row0 = (frag & 15) * 16 + (lane >> 5) * 8;
        const int col = (frag >> 4) * 32 + (lane & 31);
        #pragma unroll
        for (int j = 0; j < 8; ++j) v[j] = (_Float16)w1[(row0 + j) * 256 + col];
        *reinterpret_cast<f16x8*>(&wb1[frag * 512 + lane * 8]) = *reinterpret_cast<f16x8*>(v);
    } else if (frag < 192) {          // w2: 4 ft2 x 16 ks
        const int f = frag - 128;
        const int row0 = (f & 15) * 16 + (lane >> 5) * 8;
        const int col = (f >> 4) * 32 + (lane & 31);
        #pragma unroll
        for (int j = 0; j < 8; ++j) v[j] = (_Float16)w2[(row0 + j) * 128 + col];
        *reinterpret_cast<f16x8*>(&wb2[f * 512 + lane * 8]) = *reinterpret_cast<f16x8*>(v);
    }
}

// ---- fused MLP: 128 edges/block, 1024 thr (16 waves), plain-fp16 1-MFMA GEMMs ----
// X16: gather from pre-converted fp16 x (footprint 25.6MB -> L3-resident).
// HARD CONSTRAINT (R2-R16): LDS > 80KB -> ONE resident block/CU (2 blocks/CU
// corrupts ~0.04 regardless of numerics). hh carries +16KB pad -> 96KB.
// STRAIGHT-LINE single-tile body (R17/R18: loops/lambdas at 1024 thr spill).
template<bool X16>
__global__ __launch_bounds__(1024, 4) void edge_mlp(
    const float* __restrict__ x, const _Float16* __restrict__ x16,
    const int* __restrict__ ei,
    const float* __restrict__ ln0_g, const float* __restrict__ ln0_b,
    const _Float16* __restrict__ wb1, const float* __restrict__ b1,
    const float* __restrict__ ln1_g, const float* __restrict__ ln1_b,
    const _Float16* __restrict__ wb2, const float* __restrict__ b2,
    const float* __restrict__ ln2_g, const float* __restrict__ ln2_b,
    const float* __restrict__ wp, const float* __restrict__ bp,
    const float* __restrict__ ww, const float* __restrict__ bw,
    float* __restrict__ out, int E)
{
    __shared__ __align__(16) _Float16 hh[128 * 264 + 8192];  // 67.6KB + 16KB pad
    __shared__ __align__(8) float red[16][64][2];   // 8KB
    __shared__ __align__(8) float red2[16][32][2];  // 4KB  (total ~96KB)

    const int tid = threadIdx.x, lane = tid & 63, w = tid >> 6;   // w in 0..15
    const int l31 = lane & 31, lh = lane >> 5;
    const int ft = w >> 1, ep = w & 1;       // GEMM1: feats ft*32..+32, edges ep*64..+64
    const int ft2 = w >> 2, et2 = w & 3;     // GEMM2: feats ft2*32..+32, edges et2*32..+32
    const long base = (long)blockIdx.x * 128;

    // ---------- P1: wave-local sidx + gather + LN0 -> h0 (fp16, single plane) ----------
    {
        int si = 0;
        if (lane < 16) {
            const long idx = base + w * 8 + (lane >> 1);
            const int s = lane & 1;
            si = (idx < E) ? ei[(long)s * E + idx] : 0;
        }
        const int c = 2 * lane;
        const float ga = ln0_g[c], gb = ln0_g[c + 1], gc = ln0_g[128 + c], gd = ln0_g[129 + c];
        const float ba = ln0_b[c], bb = ln0_b[c + 1], bc = ln0_b[128 + c], bd = ln0_b[129 + c];
        char* hhc = (char*)hh;
        #pragma unroll
        for (int e8 = 0; e8 < 8; ++e8) {
            const int s0 = __shfl(si, e8 * 2 + 0);
            const int s1 = __shfl(si, e8 * 2 + 1);
            const int e = w * 8 + e8;
            float2 sv, dv;
            if constexpr (X16) {
                const f16x2v a2 = *reinterpret_cast<const f16x2v*>(&x16[(long)s0 * 128 + c]);
                const f16x2v d2 = *reinterpret_cast<const f16x2v*>(&x16[(long)s1 * 128 + c]);
                sv.x = (float)a2[0]; sv.y = (float)a2[1];
                dv.x = (float)d2[0]; dv.y = (float)d2[1];
            } else {
                sv = *reinterpret_cast<const float2*>(&x[(long)s0 * 128 + c]);
                dv = *reinterpret_cast<const float2*>(&x[(long)s1 * 128 + c]);
            }
            const float a0 = sv.x + dv.x, a1 = sv.y + dv.y;
            const float m0 = sv.x * dv.x, m1 = sv.y * dv.y;
            float s = a0 + a1 + m0 + m1;
            float q = a0 * a0 + a1 * a1 + m0 * m0 + m1 * m1;
            #pragma unroll
            for (int o = 32; o; o >>= 1) { s += __shfl_xor(s, o); q += __shfl_xor(q, o); }
            const float mu = s * (1.f / 256.f);
            const float rs = rsqrtf(q * (1.f / 256.f) - mu * mu + EPS);
            f16x2v p0, p1;
            p0[0] = (_Float16)((a0 - mu) * rs * ga + ba);
            p0[1] = (_Float16)((a1 - mu) * rs * gb + bb);
            p1[0] = (_Float16)((m0 - mu) * rs * gc + bc);
            p1[1] = (_Float16)((m1 - mu) * rs * gd + bd);
            const int o0 = e * PITCH + 4 * lane;
            const int o1 = e * PITCH + 256 + 4 * lane;
            *reinterpret_cast<f16x2v*>(hhc + o0) = p0;
            *reinterpret_cast<f16x2v*>(hhc + o1) = p1;
        }
    }
    __syncthreads();   // [1]

    // ---------- B0: GEMM1 32x32x16 fp16 (reads h0) + bias + LN1 stats partial ----------
    f32x16 acc1[2] = {};
    {
        const char* hhc = (const char*)hh;
        const int boffA = (ep * 64 + l31) * PITCH + lh * 16;
        const int boffB = (ep * 64 + 32 + l31) * PITCH + lh * 16;
        for (int ks = 0; ks < 16; ++ks) {
            const f16x8 a = *reinterpret_cast<const f16x8*>(&wb1[(ft * 16 + ks) * 512 + lane * 8]);
            const f16x8 bA = *reinterpret_cast<const f16x8*>(hhc + boffA + ks * 32);
            acc1[0] = __builtin_amdgcn_mfma_f32_32x32x16_f16(a, bA, acc1[0], 0, 0, 0);
            const f16x8 bB = *reinterpret_cast<const f16x8*>(hhc + boffB + ks * 32);
            acc1[1] = __builtin_amdgcn_mfma_f32_32x32x16_f16(a, bB, acc1[1], 0, 0, 0);
        }
        float bi[4][4];
        #pragma unroll
        for (int g2 = 0; g2 < 4; ++g2)
            *reinterpret_cast<float4*>(bi[g2]) =
                *reinterpret_cast<const float4*>(&b1[ft * 32 + g2 * 8 + 4 * lh]);
        #pragma unroll
        for (int t = 0; t < 2; ++t) {
            float s = 0.f, q = 0.f;
            #pragma unroll
            for (int r = 0; r < 16; ++r) {
                const float v2 = acc1[t][r] + bi[r >> 2][r & 3];
                acc1[t][r] = v2; s += v2; q += v2 * v2;
            }
            s += __shfl_xor(s, 32); q += __shfl_xor(q, 32);
            if (lane < 32) { red[w][t * 32 + lane][0] = s; red[w][t * 32 + lane][1] = q; }
        }
    }
    __syncthreads();   // [2]

    // ---------- B1: per-lane LN1 finalize + apply + relu -> h1 (overlays h0) ----------
    {
        char* hhc = (char*)hh;
        #pragma unroll
        for (int t = 0; t < 2; ++t) {
            const int el = t * 32 + l31;
            const int e1 = ep * 64 + el;
            float S = 0.f, Q = 0.f;
            #pragma unroll
            for (int f = 0; f < 8; ++f) { S += red[2 * f + ep][el][0]; Q += red[2 * f + ep][el][1]; }
            const float mu = S * (1.f / 256.f);
            const float rs = rsqrtf(Q * (1.f / 256.f) - mu * mu + EPS);
            #pragma unroll
            for (int g2 = 0; g2 < 4; ++g2) {
                const int f0 = ft * 32 + g2 * 8 + 4 * lh;
                float gv[4], bv[4];
                *reinterpret_cast<float4*>(gv) = *reinterpret_cast<const float4*>(&ln1_g[f0]);
                *reinterpret_cast<float4*>(bv) = *reinterpret_cast<const float4*>(&ln1_b[f0]);
                f16x4v pk;
                #pragma unroll
                for (int ii = 0; ii < 4; ++ii)
                    pk[ii] = (_Float16)fmaxf((acc1[t][g2 * 4 + ii] - mu) * rs * gv[ii] + bv[ii], 0.f);
                *reinterpret_cast<f16x4v*>(hhc + e1 * PITCH + f0 * 2) = pk;
            }
        }
    }
    __syncthreads();   // [3]

    // ---------- B2: GEMM2 32x32x16 fp16 (reads h1) + bias + LN2 stats partial ----------
    f32x16 acc2 = {};
    {
        const char* hhc = (const char*)hh;
        const int e2 = et2 * 32 + l31;
        const int boff2 = e2 * PITCH + lh * 16;
        for (int ks = 0; ks < 16; ++ks) {
            const f16x8 a = *reinterpret_cast<const f16x8*>(&wb2[(ft2 * 16 + ks) * 512 + lane * 8]);
            const f16x8 b = *reinterpret_cast<const f16x8*>(hhc + boff2 + ks * 32);
            acc2 = __builtin_amdgcn_mfma_f32_32x32x16_f16(a, b, acc2, 0, 0, 0);
        }
        float bi[4][4];
        #pragma unroll
        for (int g2 = 0; g2 < 4; ++g2)
            *reinterpret_cast<float4*>(bi[g2]) =
                *reinterpret_cast<const float4*>(&b2[ft2 * 32 + g2 * 8 + 4 * lh]);
        float s = 0.f, q = 0.f;
        #pragma unroll
        for (int r = 0; r < 16; ++r) {
            const float v2 = acc2[r] + bi[r >> 2][r & 3];
            acc2[r] = v2; s += v2; q += v2 * v2;
        }
        s += __shfl_xor(s, 32); q += __shfl_xor(q, 32);
        if (lane < 32) { red[w][lane][0] = s; red[w][lane][1] = q; }
    }
    __syncthreads();   // [4]

    // ---------- B3: per-lane LN2 finalize + apply + heads partial -> red2 ----------
    {
        float S = 0.f, Q = 0.f;
        #pragma unroll
        for (int f2 = 0; f2 < 4; ++f2) { S += red[4 * f2 + et2][l31][0]; Q += red[4 * f2 + et2][l31][1]; }
        const float mu = S * (1.f / 128.f);
        const float rs = rsqrtf(Q * (1.f / 128.f) - mu * mu + EPS);
        float pp = 0.f, ws2 = 0.f;
        #pragma unroll
        for (int g2 = 0; g2 < 4; ++g2) {
            const int f0 = ft2 * 32 + g2 * 8 + 4 * lh;
            float gv[4], bv[4], pv[4], wv[4];
            *reinterpret_cast<float4*>(gv) = *reinterpret_cast<const float4*>(&ln2_g[f0]);
            *reinterpret_cast<float4*>(bv) = *reinterpret_cast<const float4*>(&ln2_b[f0]);
            *reinterpret_cast<float4*>(pv) = *reinterpret_cast<const float4*>(&wp[f0]);
            *reinterpret_cast<float4*>(wv) = *reinterpret_cast<const float4*>(&ww[f0]);
            #pragma unroll
            for (int ii = 0; ii < 4; ++ii) {
                const float t = fmaxf((acc2[g2 * 4 + ii] - mu) * rs * gv[ii] + bv[ii], 0.f);
                pp += t * pv[ii]; ws2 += t * wv[ii];
            }
        }
        pp += __shfl_xor(pp, 32); ws2 += __shfl_xor(ws2, 32);
        if (lane < 32) { red2[w][lane][0] = pp; red2[w][lane][1] = ws2; }
    }
    __syncthreads();   // [5]

    // ---------- B4: output ----------
    if (tid < 128 && base + tid < E) {
        const int q5 = tid >> 5, l = tid & 31;
        float P = bp[0], W = bw[0];
        #pragma unroll
        for (int f2 = 0; f2 < 4; ++f2) { P += red2[4 * f2 + q5][l][0]; W += red2[4 * f2 + q5][l][1]; }
        out[base + tid] = P;                         // logits
        out[(long)E + base + tid] = fmaxf(W, 0.f);   // relu'd weights
    }
}

extern "C" void kernel_launch(void* const* d_in, const int* in_sizes, int n_in,
                              void* d_out, int out_size, void* d_ws, size_t ws_size,
                              hipStream_t stream) {
    const float* x     = (const float*)d_in[0];
    const int*   ei    = (const int*)  d_in[1];
    const float* ln0_g = (const float*)d_in[2];
    const float* ln0_b = (const float*)d_in[3];
    const float* w1    = (const float*)d_in[4];
    const float* b1    = (const float*)d_in[5];
    const float* ln1_g = (const float*)d_in[6];
    const float* ln1_b = (const float*)d_in[7];
    const float* w2    = (const float*)d_in[8];
    const float* b2    = (const float*)d_in[9];
    const float* ln2_g = (const float*)d_in[10];
    const float* ln2_b = (const float*)d_in[11];
    const float* wp    = (const float*)d_in[12];
    const float* bp    = (const float*)d_in[13];
    const float* ww    = (const float*)d_in[14];
    const float* bw    = (const float*)d_in[15];

    _Float16* wb1 = (_Float16*)d_ws;        // 128 frags * 512 = 128KB
    _Float16* wb2 = wb1 + 128 * 512;        // 64 frags * 512 = 64KB
    _Float16* x16 = wb2 + 64 * 512;         // node features in fp16

    const int E = in_sizes[1] / 2;
    const long xN = (long)in_sizes[0];      // N*D elements
    const size_t need = 192 * 1024 + (size_t)xN * sizeof(_Float16);

    prep_weights<<<48, 256, 0, stream>>>(w1, w2, wb1, wb2);
    if (ws_size >= need) {
        const int nb = (int)((xN / 8 + 255) / 256);
        prep_x<<<nb, 256, 0, stream>>>(x, x16, xN);
        edge_mlp<true><<<(E + 127) / 128, 1024, 0, stream>>>(
            x, x16, ei, ln0_g, ln0_b, wb1, b1, ln1_g, ln1_b, wb2, b2,
            ln2_g, ln2_b, wp, bp, ww, bw, (float*)d_out, E);
    } else {
        edge_mlp<false><<<(E + 127) / 128, 1024, 0, stream>>>(
            x, x16, ei, ln0_g, ln0_b, wb1, b1, ln1_g, ln1_b, wb2, b2,
            ln2_g, ln2_b, wp, bp, ww, bw, (float*)d_out, E);
    }
}